// Round 1
// baseline (1131.318 us; speedup 1.0000x reference)
//
#include <hip/hip_runtime.h>

typedef _Float16 f16x8 __attribute__((ext_vector_type(8)));
typedef float f32x4 __attribute__((ext_vector_type(4)));

// ---- LDS layout (bytes). Total 152576 <= 163840 (gfx950 addressable LDS) ----
// A    : [64][264] f16  @ 0       (33792 B)   x-tokens; later aliased by ao (same layout)
// HEADS: 8 * 10240      @ 33792   (81920 B)   per head: q[64][40], k[64][40];
//                                             later aliased per-head by P[64][72] (9216 B);
//                                             later aliased by outF fp32 [64][260] (66560 B)
// VT   : 8 * 4608       @ 115712  (36864 B)   per head: v^T [32][72]
#define A_OFF        0
#define A_STRIDE     264
#define HEADS_OFF    33792
#define HEAD_BYTES   10240
#define QK_STRIDE    40
#define P_STRIDE     72
#define VT_OFF       115712
#define VT_HEAD_B    4608
#define VT_STRIDE    72
#define OUTF_OFF     33792
#define OUTF_STRIDE  260
#define LDS_BYTES    152576

__device__ __forceinline__ f16x8 pack8(float4 a, float4 b) {
  f16x8 r;
  r[0] = (_Float16)a.x; r[1] = (_Float16)a.y; r[2] = (_Float16)a.z; r[3] = (_Float16)a.w;
  r[4] = (_Float16)b.x; r[5] = (_Float16)b.y; r[6] = (_Float16)b.z; r[7] = (_Float16)b.w;
  return r;
}

__global__ __launch_bounds__(512, 2) void win_attn_kernel(
    const float* __restrict__ x, const float* __restrict__ wqkv,
    const float* __restrict__ bqkv, const float* __restrict__ wproj,
    const float* __restrict__ bproj, float* __restrict__ out)
{
  __shared__ __align__(16) char smem[LDS_BYTES];

  const int tid  = threadIdx.x;
  const int lane = tid & 63;
  const int wv   = tid >> 6;      // wave id 0..7 == head id
  const int c16  = lane & 15;     // tile column
  const int quad = lane >> 4;     // 0..3

  const int wb = blockIdx.x;
  const int b  = wb >> 8;
  const int hn = (wb >> 4) & 15;
  const int wn = wb & 15;
  // base of this window in x/out: [b][c=0][hn*8][wn*8]
  const size_t xbase = (size_t)b * (256 * 16384) + (size_t)(hn * 8) * 128 + (size_t)(wn * 8);

  // ============ stage 1: load x window -> A (f16, token-major) ============
  {
    _Float16* A = (_Float16*)&smem[A_OFF];
    const int i = lane >> 3, j = lane & 7;     // token t = lane
    const size_t sp = xbase + (size_t)i * 128 + j;
    for (int s = 0; s < 32; ++s) {
      int c = wv * 32 + s;
      float v = x[sp + (size_t)c * 16384];
      A[lane * A_STRIDE + c] = (_Float16)v;
    }
  }
  __syncthreads();

  // ============ stage 2: qkv GEMM, wave wv computes head wv's q,k,v ============
  {
    const _Float16* A = (const _Float16*)&smem[A_OFF];
    int nb[6];
    nb[0] = 32 * wv;        nb[1] = 32 * wv + 16;
    nb[2] = 256 + 32 * wv;  nb[3] = 256 + 32 * wv + 16;
    nb[4] = 512 + 32 * wv;  nb[5] = 512 + 32 * wv + 16;

    f32x4 acc[6][4];
    for (int nt = 0; nt < 6; ++nt)
      for (int mt = 0; mt < 4; ++mt)
        acc[nt][mt] = (f32x4){0.f, 0.f, 0.f, 0.f};

    const float* wrow[6];
    for (int nt = 0; nt < 6; ++nt)
      wrow[nt] = wqkv + (size_t)(nb[nt] + c16) * 256 + quad * 8;

    for (int k0 = 0; k0 < 256; k0 += 32) {
      f16x8 af[4];
      for (int mt = 0; mt < 4; ++mt)
        af[mt] = *(const f16x8*)&A[(mt * 16 + c16) * A_STRIDE + k0 + quad * 8];
      for (int nt = 0; nt < 6; ++nt) {
        const float* p = wrow[nt] + k0;
        float4 b0 = *(const float4*)p;
        float4 b1 = *(const float4*)(p + 4);
        f16x8 bf = pack8(b0, b1);
        for (int mt = 0; mt < 4; ++mt)
          acc[nt][mt] = __builtin_amdgcn_mfma_f32_16x16x32_f16(af[mt], bf, acc[nt][mt], 0, 0, 0);
      }
    }

    _Float16* qh  = (_Float16*)&smem[HEADS_OFF + wv * HEAD_BYTES];
    _Float16* kh  = qh + 64 * QK_STRIDE;
    _Float16* vth = (_Float16*)&smem[VT_OFF + wv * VT_HEAD_B];
    for (int nt = 0; nt < 6; ++nt) {
      float bias = bqkv[nb[nt] + c16];
      for (int mt = 0; mt < 4; ++mt) {
        for (int r = 0; r < 4; ++r) {
          float val = acc[nt][mt][r] + bias;
          int t = mt * 16 + (quad << 2) + r;
          if (nt < 2)       qh[t * QK_STRIDE + nt * 16 + c16] = (_Float16)val;
          else if (nt < 4)  kh[t * QK_STRIDE + (nt - 2) * 16 + c16] = (_Float16)val;
          else              vth[((nt - 4) * 16 + c16) * VT_STRIDE + t] = (_Float16)val;
        }
      }
    }
  }
  __syncthreads();

  // ============ stage 3: attention for head wv (wave-local) ============
  {
    const _Float16* qh  = (const _Float16*)&smem[HEADS_OFF + wv * HEAD_BYTES];
    const _Float16* kh  = qh + 64 * QK_STRIDE;
    const _Float16* vth = (const _Float16*)&smem[VT_OFF + wv * VT_HEAD_B];

    f16x8 qf[4], kf[4];
    for (int mt = 0; mt < 4; ++mt)
      qf[mt] = *(const f16x8*)&qh[(mt * 16 + c16) * QK_STRIDE + quad * 8];
    for (int nt = 0; nt < 4; ++nt)
      kf[nt] = *(const f16x8*)&kh[(nt * 16 + c16) * QK_STRIDE + quad * 8];

    f32x4 S[4][4];
    for (int mt = 0; mt < 4; ++mt)
      for (int nt = 0; nt < 4; ++nt)
        S[mt][nt] = __builtin_amdgcn_mfma_f32_16x16x32_f16(
            qf[mt], kf[nt], (f32x4){0.f, 0.f, 0.f, 0.f}, 0, 0, 0);

    // softmax over k (row-wise); rows of C-layout live in quads -> shuffle-reduce
    const float kExpScale = 0.25506973288423525f;  // (1/sqrt(32)) * log2(e)
    float rinv[4][4];
    _Float16* P = (_Float16*)&smem[HEADS_OFF + wv * HEAD_BYTES];  // overwrites q,k (done)
    for (int mt = 0; mt < 4; ++mt) {
      for (int r = 0; r < 4; ++r) {
        float s0 = S[mt][0][r], s1 = S[mt][1][r], s2 = S[mt][2][r], s3 = S[mt][3][r];
        float mx = fmaxf(fmaxf(s0, s1), fmaxf(s2, s3));
        mx = fmaxf(mx, __shfl_xor(mx, 1));
        mx = fmaxf(mx, __shfl_xor(mx, 2));
        mx = fmaxf(mx, __shfl_xor(mx, 4));
        mx = fmaxf(mx, __shfl_xor(mx, 8));
        float p0 = exp2f((s0 - mx) * kExpScale);
        float p1 = exp2f((s1 - mx) * kExpScale);
        float p2 = exp2f((s2 - mx) * kExpScale);
        float p3 = exp2f((s3 - mx) * kExpScale);
        float sum = p0 + p1 + p2 + p3;
        sum += __shfl_xor(sum, 1);
        sum += __shfl_xor(sum, 2);
        sum += __shfl_xor(sum, 4);
        sum += __shfl_xor(sum, 8);
        rinv[mt][r] = 1.0f / sum;
        int t = mt * 16 + (quad << 2) + r;
        P[t * P_STRIDE +  0 + c16] = (_Float16)p0;
        P[t * P_STRIDE + 16 + c16] = (_Float16)p1;
        P[t * P_STRIDE + 32 + c16] = (_Float16)p2;
        P[t * P_STRIDE + 48 + c16] = (_Float16)p3;
      }
    }

    // O = P @ V  (K = 64 tokens, two K-steps)
    f32x4 O[4][2];
    for (int mt = 0; mt < 4; ++mt)
      for (int n2 = 0; n2 < 2; ++n2)
        O[mt][n2] = (f32x4){0.f, 0.f, 0.f, 0.f};
    for (int kk = 0; kk < 2; ++kk) {
      f16x8 pf[4];
      for (int mt = 0; mt < 4; ++mt)
        pf[mt] = *(const f16x8*)&P[(mt * 16 + c16) * P_STRIDE + kk * 32 + quad * 8];
      for (int n2 = 0; n2 < 2; ++n2) {
        f16x8 vf = *(const f16x8*)&vth[(n2 * 16 + c16) * VT_STRIDE + kk * 32 + quad * 8];
        for (int mt = 0; mt < 4; ++mt)
          O[mt][n2] = __builtin_amdgcn_mfma_f32_16x16x32_f16(pf[mt], vf, O[mt][n2], 0, 0, 0);
      }
    }

    // ao[t][h*32+d] (aliases A; all waves left stage 2 at the barrier)
    _Float16* ao = (_Float16*)&smem[A_OFF];
    for (int mt = 0; mt < 4; ++mt) {
      for (int n2 = 0; n2 < 2; ++n2) {
        for (int r = 0; r < 4; ++r) {
          int t = mt * 16 + (quad << 2) + r;
          int c = wv * 32 + n2 * 16 + c16;
          ao[t * A_STRIDE + c] = (_Float16)(O[mt][n2][r] * rinv[mt][r]);
        }
      }
    }
  }
  __syncthreads();

  // ============ stage 4: proj GEMM, wave wv -> output cols [32wv, 32wv+32) ============
  {
    const _Float16* ao = (const _Float16*)&smem[A_OFF];
    const int nbase = wv * 32;
    f32x4 acc[2][4];
    for (int nt = 0; nt < 2; ++nt)
      for (int mt = 0; mt < 4; ++mt)
        acc[nt][mt] = (f32x4){0.f, 0.f, 0.f, 0.f};

    const float* wrow[2];
    for (int nt = 0; nt < 2; ++nt)
      wrow[nt] = wproj + (size_t)(nbase + nt * 16 + c16) * 256 + quad * 8;

    for (int k0 = 0; k0 < 256; k0 += 32) {
      f16x8 af[4];
      for (int mt = 0; mt < 4; ++mt)
        af[mt] = *(const f16x8*)&ao[(mt * 16 + c16) * A_STRIDE + k0 + quad * 8];
      for (int nt = 0; nt < 2; ++nt) {
        const float* p = wrow[nt] + k0;
        float4 b0 = *(const float4*)p;
        float4 b1 = *(const float4*)(p + 4);
        f16x8 bf = pack8(b0, b1);
        for (int mt = 0; mt < 4; ++mt)
          acc[nt][mt] = __builtin_amdgcn_mfma_f32_16x16x32_f16(af[mt], bf, acc[nt][mt], 0, 0, 0);
      }
    }

    // write to fp32 staging (aliases HEADS region; stage-3 P reads done at barrier)
    float* outF = (float*)&smem[OUTF_OFF];
    for (int nt = 0; nt < 2; ++nt) {
      float bias = bproj[nbase + nt * 16 + c16];
      for (int mt = 0; mt < 4; ++mt) {
        for (int r = 0; r < 4; ++r) {
          int t = mt * 16 + (quad << 2) + r;
          int c = nbase + nt * 16 + c16;
          outF[t * OUTF_STRIDE + c] = acc[nt][mt][r] + bias;
        }
      }
    }
  }
  __syncthreads();

  // ============ epilogue: coalesced global write ============
  {
    const float* outF = (const float*)&smem[OUTF_OFF];
    const int i = lane >> 3, j = lane & 7;   // token t = lane
    const size_t sp = xbase + (size_t)i * 128 + j;
    for (int s = 0; s < 32; ++s) {
      int c = wv * 32 + s;
      out[sp + (size_t)c * 16384] = outF[lane * OUTF_STRIDE + c];
    }
  }
}

extern "C" void kernel_launch(void* const* d_in, const int* in_sizes, int n_in,
                              void* d_out, int out_size, void* d_ws, size_t ws_size,
                              hipStream_t stream) {
  (void)in_sizes; (void)n_in; (void)d_ws; (void)ws_size; (void)out_size;
  const float* x     = (const float*)d_in[0];
  const float* wqkv  = (const float*)d_in[1];
  const float* bqkv  = (const float*)d_in[2];
  const float* wproj = (const float*)d_in[3];
  const float* bproj = (const float*)d_in[4];
  float* out = (float*)d_out;
  hipLaunchKernelGGL(win_attn_kernel, dim3(4096), dim3(512), 0, stream,
                     x, wqkv, bqkv, wproj, bproj, out);
}

// Round 2
// 1113.639 us; speedup vs baseline: 1.0159x; 1.0159x over previous
//
#include <hip/hip_runtime.h>

typedef _Float16 f16x8 __attribute__((ext_vector_type(8)));
typedef _Float16 f16x4 __attribute__((ext_vector_type(4)));
typedef float f32x4 __attribute__((ext_vector_type(4)));

// LDS: x-tile A[64][264] f16 (33792 B), later reused as ao[64][264].
// Stride 264 f16 = 528 B = 132 banks ≡ 4 mod 32 → b128 row reads are 2-way (free).
#define A_STRIDE 264
#define LDS_BYTES (64 * A_STRIDE * 2)

__device__ __forceinline__ float packh2(float x, float y) {
  union { float f; _Float16 h[2]; } u;
  u.h[0] = (_Float16)x; u.h[1] = (_Float16)y;
  return u.f;
}

// Quad-regroup: source C-layout regs hold X[R][L] with R = 16*mt + 4*quad + r,
// L = lane&15. lo*/hi* are packed pairs (r=0,1 | r=2,3) of tiles mt=2kk and 2kk+1.
// Returns operand frag: lane (c16,q) gets X[32kk + 8q + j][c16], j=0..7.
__device__ __forceinline__ f16x8 regroup(float lo0, float lo1, float hi0, float hi1,
                                         int c16, int q) {
  int sA = c16 | ((q & 1) << 5);   // lane c16 + 16*(2*(q&1))   -> j=0..3
  int sB = sA | 16;                // lane c16 + 16*(2*(q&1)+1) -> j=4..7
  float a0 = __shfl(lo0, sA), a1 = __shfl(lo1, sA);
  float a2 = __shfl(hi0, sA), a3 = __shfl(hi1, sA);
  float b0 = __shfl(lo0, sB), b1 = __shfl(lo1, sB);
  float b2 = __shfl(hi0, sB), b3 = __shfl(hi1, sB);
  bool hi = q >= 2;                // mt = 2kk + (q>>1)
  float4 f;
  f.x = hi ? a2 : a0; f.y = hi ? a3 : a1;
  f.z = hi ? b2 : b0; f.w = hi ? b3 : b1;
  union { float4 v; f16x8 h; } u; u.v = f;
  return u.h;
}

__global__ __launch_bounds__(256) void convert_weights_kernel(
    const float* __restrict__ wqkv, const float* __restrict__ wproj,
    _Float16* __restrict__ dst) {
  int i = blockIdx.x * 256 + threadIdx.x;   // 65536 threads, 4 floats each
  float4 v;
  if (i < 49152) v = ((const float4*)wqkv)[i];
  else           v = ((const float4*)wproj)[i - 49152];
  f16x4 h;
  h[0] = (_Float16)v.x; h[1] = (_Float16)v.y;
  h[2] = (_Float16)v.z; h[3] = (_Float16)v.w;
  *(f16x4*)&dst[4 * i] = h;
}

__global__ __launch_bounds__(512, 4) void win_attn_kernel(
    const float* __restrict__ x, const _Float16* __restrict__ Wh,
    const float* __restrict__ bqkv, const float* __restrict__ bproj,
    float* __restrict__ out)
{
  __shared__ __align__(16) char smem[LDS_BYTES];
  _Float16* A = (_Float16*)smem;

  const int tid  = threadIdx.x;
  const int lane = tid & 63;
  const int wv   = tid >> 6;      // wave id == head id
  const int c16  = lane & 15;
  const int q    = lane >> 4;     // quad 0..3

  // XCD-pair swizzle: block ids g*16+s and g*16+s+8 (same XCD under mod-8 rr)
  // map to horizontally adjacent windows 2j, 2j+1 (they share 64-B x lines).
  const int id = blockIdx.x;
  const int g = id >> 4, s = id & 15;
  const int w = (g << 4) | ((s & 7) << 1) | (s >> 3);
  const int b  = w >> 8;
  const int hn = (w >> 4) & 15;
  const int wn = w & 15;
  const size_t xbase = (size_t)b * (256 * 16384) + (size_t)(hn * 8) * 128 + (size_t)(wn * 8);

  // ---- stage 1: x window -> A f16 [token][channel] ----
  {
    const int i = lane >> 3, j = lane & 7;          // token = lane
    const size_t sp = xbase + (size_t)i * 128 + j;
    #pragma unroll
    for (int ss = 0; ss < 16; ++ss) {
      int c = wv * 32 + ss * 2;
      float v0 = x[sp + (size_t)c * 16384];
      float v1 = x[sp + (size_t)(c + 1) * 16384];
      *(float*)&A[lane * A_STRIDE + c] = packh2(v0, v1);
    }
  }
  __syncthreads();

  // ---- stage 2a: q,k via swapped GEMM  D[d][t] = W . x^T ----
  f16x8 qf[4], kf[4];   // operand frags: lane&15 = token, regs = d (8q+j)
  {
    f32x4 aq[2][4], ak[2][4];   // [md][nt]
    #pragma unroll
    for (int md = 0; md < 2; ++md)
      #pragma unroll
      for (int nt = 0; nt < 4; ++nt) {
        aq[md][nt] = (f32x4){0.f,0.f,0.f,0.f};
        ak[md][nt] = (f32x4){0.f,0.f,0.f,0.f};
      }
    const _Float16* Wq = Wh + (size_t)(32 * wv) * 256;
    const _Float16* Wk = Wh + (size_t)(256 + 32 * wv) * 256;
    #pragma unroll
    for (int k0 = 0; k0 < 8; ++k0) {
      f16x8 xf[4];
      #pragma unroll
      for (int nt = 0; nt < 4; ++nt)
        xf[nt] = *(const f16x8*)&A[(nt * 16 + c16) * A_STRIDE + k0 * 32 + q * 8];
      f16x8 wq0 = *(const f16x8*)&Wq[(c16) * 256 + k0 * 32 + q * 8];
      f16x8 wq1 = *(const f16x8*)&Wq[(16 + c16) * 256 + k0 * 32 + q * 8];
      f16x8 wk0 = *(const f16x8*)&Wk[(c16) * 256 + k0 * 32 + q * 8];
      f16x8 wk1 = *(const f16x8*)&Wk[(16 + c16) * 256 + k0 * 32 + q * 8];
      #pragma unroll
      for (int nt = 0; nt < 4; ++nt) {
        aq[0][nt] = __builtin_amdgcn_mfma_f32_16x16x32_f16(wq0, xf[nt], aq[0][nt], 0, 0, 0);
        aq[1][nt] = __builtin_amdgcn_mfma_f32_16x16x32_f16(wq1, xf[nt], aq[1][nt], 0, 0, 0);
        ak[0][nt] = __builtin_amdgcn_mfma_f32_16x16x32_f16(wk0, xf[nt], ak[0][nt], 0, 0, 0);
        ak[1][nt] = __builtin_amdgcn_mfma_f32_16x16x32_f16(wk1, xf[nt], ak[1][nt], 0, 0, 0);
      }
    }
    // bias (d = 16*md + 4*q + r) then regroup to operand frags
    #pragma unroll
    for (int md = 0; md < 2; ++md) {
      float4 bq = *(const float4*)&bqkv[32 * wv + md * 16 + 4 * q];
      float4 bk = *(const float4*)&bqkv[256 + 32 * wv + md * 16 + 4 * q];
      #pragma unroll
      for (int nt = 0; nt < 4; ++nt) {
        aq[md][nt][0] += bq.x; aq[md][nt][1] += bq.y; aq[md][nt][2] += bq.z; aq[md][nt][3] += bq.w;
        ak[md][nt][0] += bk.x; ak[md][nt][1] += bk.y; ak[md][nt][2] += bk.z; ak[md][nt][3] += bk.w;
      }
    }
    #pragma unroll
    for (int nt = 0; nt < 4; ++nt) {
      qf[nt] = regroup(packh2(aq[0][nt][0], aq[0][nt][1]), packh2(aq[0][nt][2], aq[0][nt][3]),
                       packh2(aq[1][nt][0], aq[1][nt][1]), packh2(aq[1][nt][2], aq[1][nt][3]),
                       c16, q);
      kf[nt] = regroup(packh2(ak[0][nt][0], ak[0][nt][1]), packh2(ak[0][nt][2], ak[0][nt][3]),
                       packh2(ak[1][nt][0], ak[1][nt][1]), packh2(ak[1][nt][2], ak[1][nt][3]),
                       c16, q);
    }
  }

  // ---- stage 2b: v via token-major GEMM  D[t][d] = x . W_v^T ----
  f16x8 vf[2][2];   // [d-tile][kk]: V^T frags, lane&15 = d, regs = u (8q+j)
  {
    f32x4 av[4][2];   // [mu][nd]
    #pragma unroll
    for (int mu = 0; mu < 4; ++mu)
      #pragma unroll
      for (int nd = 0; nd < 2; ++nd)
        av[mu][nd] = (f32x4){0.f,0.f,0.f,0.f};
    const _Float16* Wv = Wh + (size_t)(512 + 32 * wv) * 256;
    #pragma unroll
    for (int k0 = 0; k0 < 8; ++k0) {
      f16x8 xf[4];
      #pragma unroll
      for (int mu = 0; mu < 4; ++mu)
        xf[mu] = *(const f16x8*)&A[(mu * 16 + c16) * A_STRIDE + k0 * 32 + q * 8];
      f16x8 wv0 = *(const f16x8*)&Wv[(c16) * 256 + k0 * 32 + q * 8];
      f16x8 wv1 = *(const f16x8*)&Wv[(16 + c16) * 256 + k0 * 32 + q * 8];
      #pragma unroll
      for (int mu = 0; mu < 4; ++mu) {
        av[mu][0] = __builtin_amdgcn_mfma_f32_16x16x32_f16(xf[mu], wv0, av[mu][0], 0, 0, 0);
        av[mu][1] = __builtin_amdgcn_mfma_f32_16x16x32_f16(xf[mu], wv1, av[mu][1], 0, 0, 0);
      }
    }
    #pragma unroll
    for (int nd = 0; nd < 2; ++nd) {
      float bv = bqkv[512 + 32 * wv + nd * 16 + c16];   // d = c16+16nd (lane-low)
      #pragma unroll
      for (int mu = 0; mu < 4; ++mu) {
        av[mu][nd][0] += bv; av[mu][nd][1] += bv; av[mu][nd][2] += bv; av[mu][nd][3] += bv;
      }
      float pv[4][2];
      #pragma unroll
      for (int mu = 0; mu < 4; ++mu) {
        pv[mu][0] = packh2(av[mu][nd][0], av[mu][nd][1]);
        pv[mu][1] = packh2(av[mu][nd][2], av[mu][nd][3]);
      }
      #pragma unroll
      for (int kk = 0; kk < 2; ++kk)
        vf[nd][kk] = regroup(pv[2*kk][0], pv[2*kk][1], pv[2*kk+1][0], pv[2*kk+1][1], c16, q);
    }
  }

  // ---- stage 3: S^T = K.Q^T, softmax over u (regs+quads), O^T = V^T.P^T ----
  f32x4 O[2][4];     // [md(d)][nt(t)]
  float rinv[4];
  {
    f32x4 S[4][4];   // [mu(u)][nt(t)]
    #pragma unroll
    for (int mu = 0; mu < 4; ++mu)
      #pragma unroll
      for (int nt = 0; nt < 4; ++nt)
        S[mu][nt] = __builtin_amdgcn_mfma_f32_16x16x32_f16(
            kf[mu], qf[nt], (f32x4){0.f,0.f,0.f,0.f}, 0, 0, 0);

    const float kExpScale = 0.25506973288423525f;  // (1/sqrt(32)) * log2(e)
    float pk_p[4][4][2];  // [nt][mu][h]
    #pragma unroll
    for (int nt = 0; nt < 4; ++nt) {
      float mx = S[0][nt][0];
      #pragma unroll
      for (int mu = 0; mu < 4; ++mu)
        #pragma unroll
        for (int r = 0; r < 4; ++r)
          mx = fmaxf(mx, S[mu][nt][r]);
      mx = fmaxf(mx, __shfl_xor(mx, 16));
      mx = fmaxf(mx, __shfl_xor(mx, 32));
      float sum = 0.f;
      #pragma unroll
      for (int mu = 0; mu < 4; ++mu)
        #pragma unroll
        for (int r = 0; r < 4; ++r) {
          float e = exp2f((S[mu][nt][r] - mx) * kExpScale);
          S[mu][nt][r] = e; sum += e;
        }
      sum += __shfl_xor(sum, 16);
      sum += __shfl_xor(sum, 32);
      rinv[nt] = 1.0f / sum;
      #pragma unroll
      for (int mu = 0; mu < 4; ++mu) {
        pk_p[nt][mu][0] = packh2(S[mu][nt][0], S[mu][nt][1]);
        pk_p[nt][mu][1] = packh2(S[mu][nt][2], S[mu][nt][3]);
      }
    }

    #pragma unroll
    for (int md = 0; md < 2; ++md)
      #pragma unroll
      for (int nt = 0; nt < 4; ++nt)
        O[md][nt] = (f32x4){0.f,0.f,0.f,0.f};
    #pragma unroll
    for (int kk = 0; kk < 2; ++kk) {
      #pragma unroll
      for (int nt = 0; nt < 4; ++nt) {
        f16x8 pf = regroup(pk_p[nt][2*kk][0], pk_p[nt][2*kk][1],
                           pk_p[nt][2*kk+1][0], pk_p[nt][2*kk+1][1], c16, q);
        O[0][nt] = __builtin_amdgcn_mfma_f32_16x16x32_f16(vf[0][kk], pf, O[0][nt], 0, 0, 0);
        O[1][nt] = __builtin_amdgcn_mfma_f32_16x16x32_f16(vf[1][kk], pf, O[1][nt], 0, 0, 0);
      }
    }
  }

  // A is dead (last read in stage 2b). Reuse as ao[t][c].
  __syncthreads();
  {
    #pragma unroll
    for (int md = 0; md < 2; ++md)
      #pragma unroll
      for (int nt = 0; nt < 4; ++nt) {
        int t = nt * 16 + c16;
        int c = 32 * wv + md * 16 + 4 * q;
        *(float*)&A[t * A_STRIDE + c]     = packh2(O[md][nt][0] * rinv[nt], O[md][nt][1] * rinv[nt]);
        *(float*)&A[t * A_STRIDE + c + 2] = packh2(O[md][nt][2] * rinv[nt], O[md][nt][3] * rinv[nt]);
      }
  }
  __syncthreads();

  // ---- stage 4: proj via swapped GEMM  D[e][t] = W_p . ao^T + direct store ----
  {
    f32x4 ap[2][4];   // [me][nt]
    #pragma unroll
    for (int me = 0; me < 2; ++me)
      #pragma unroll
      for (int nt = 0; nt < 4; ++nt)
        ap[me][nt] = (f32x4){0.f,0.f,0.f,0.f};
    const _Float16* Wp = Wh + (size_t)768 * 256 + (size_t)(32 * wv) * 256;
    #pragma unroll
    for (int k0 = 0; k0 < 8; ++k0) {
      f16x8 af[4];
      #pragma unroll
      for (int nt = 0; nt < 4; ++nt)
        af[nt] = *(const f16x8*)&A[(nt * 16 + c16) * A_STRIDE + k0 * 32 + q * 8];
      f16x8 wp0 = *(const f16x8*)&Wp[(c16) * 256 + k0 * 32 + q * 8];
      f16x8 wp1 = *(const f16x8*)&Wp[(16 + c16) * 256 + k0 * 32 + q * 8];
      #pragma unroll
      for (int nt = 0; nt < 4; ++nt) {
        ap[0][nt] = __builtin_amdgcn_mfma_f32_16x16x32_f16(wp0, af[nt], ap[0][nt], 0, 0, 0);
        ap[1][nt] = __builtin_amdgcn_mfma_f32_16x16x32_f16(wp1, af[nt], ap[1][nt], 0, 0, 0);
      }
    }
    #pragma unroll
    for (int me = 0; me < 2; ++me) {
      float4 bp = *(const float4*)&bproj[32 * wv + me * 16 + 4 * q];
      #pragma unroll
      for (int nt = 0; nt < 4; ++nt) {
        int t = nt * 16 + c16;
        size_t sp = xbase + (size_t)(t >> 3) * 128 + (t & 7);
        int e = 32 * wv + me * 16 + 4 * q;
        out[sp + (size_t)(e + 0) * 16384] = ap[me][nt][0] + bp.x;
        out[sp + (size_t)(e + 1) * 16384] = ap[me][nt][1] + bp.y;
        out[sp + (size_t)(e + 2) * 16384] = ap[me][nt][2] + bp.z;
        out[sp + (size_t)(e + 3) * 16384] = ap[me][nt][3] + bp.w;
      }
    }
  }
}

extern "C" void kernel_launch(void* const* d_in, const int* in_sizes, int n_in,
                              void* d_out, int out_size, void* d_ws, size_t ws_size,
                              hipStream_t stream) {
  (void)in_sizes; (void)n_in; (void)out_size; (void)ws_size;
  const float* x     = (const float*)d_in[0];
  const float* wqkv  = (const float*)d_in[1];
  const float* bqkv  = (const float*)d_in[2];
  const float* wproj = (const float*)d_in[3];
  const float* bproj = (const float*)d_in[4];
  float* out = (float*)d_out;
  _Float16* Wh = (_Float16*)d_ws;   // 768*256 + 256*256 f16 = 524288 B

  hipLaunchKernelGGL(convert_weights_kernel, dim3(256), dim3(256), 0, stream,
                     wqkv, wproj, Wh);
  hipLaunchKernelGGL(win_attn_kernel, dim3(4096), dim3(512), 0, stream,
                     x, Wh, bqkv, bproj, out);
}